// Round 3
// baseline (598.330 us; speedup 1.0000x reference)
//
#include <hip/hip_runtime.h>
#include <math.h>

// Problem constants
constexpr int E = 8, H = 1024, DFF = 2048, T = 4096;
constexpr int TR = 8192;          // total routed rows = T * topk
constexpr int MAXJ = 72;          // max (expert, m-tile) jobs: 8192/128 + E

typedef __bf16 bf16x8 __attribute__((ext_vector_type(8)));
typedef __bf16 bf16x4 __attribute__((ext_vector_type(4)));
typedef float f32x4 __attribute__((ext_vector_type(4)));

__device__ __forceinline__ void gload16(const void* g, void* l) {
    __builtin_amdgcn_global_load_lds(
        (const __attribute__((address_space(1))) unsigned int*)g,
        (__attribute__((address_space(3))) unsigned int*)l, 16, 0, 0);
}

// ---------------- k0: fused x->bf16 conversion + affinity/top-2 ----------------
// blocks [0,1024): affinity; blocks [1024, 1024+4096): x fp32->bf16.
__global__ __launch_bounds__(256) void k0_fused(
    const float* __restrict__ x, const float* __restrict__ cent,
    const float* __restrict__ bias,
    int* __restrict__ se, float* __restrict__ sw,
    __bf16* __restrict__ xb, int x4) {
    __shared__ float cs[E * H];
    int tid = threadIdx.x;

    if (blockIdx.x >= 1024) {
        int i = (blockIdx.x - 1024) * 256 + tid;
        if (i < x4) {
            float4 v = ((const float4*)x)[i];
            bf16x4 o = {(__bf16)v.x, (__bf16)v.y, (__bf16)v.z, (__bf16)v.w};
            ((bf16x4*)xb)[i] = o;
        }
        return;
    }

    // affinity role
    for (int i = tid; i < E * H / 4; i += 256)
        ((float4*)cs)[i] = ((const float4*)cent)[i];
    __syncthreads();

    int wave = tid >> 6, lane = tid & 63;
    int t = blockIdx.x * 4 + wave;
    const float4* xr = (const float4*)(x + (size_t)t * H);
    float acc[E] = {};
    #pragma unroll
    for (int it = 0; it < 4; it++) {
        float4 xv = xr[lane + it * 64];
        #pragma unroll
        for (int e = 0; e < E; e++) {
            float4 cv = ((const float4*)(cs + e * H))[lane + it * 64];
            acc[e] = fmaf(xv.x, cv.x, acc[e]);
            acc[e] = fmaf(xv.y, cv.y, acc[e]);
            acc[e] = fmaf(xv.z, cv.z, acc[e]);
            acc[e] = fmaf(xv.w, cv.w, acc[e]);
        }
    }
    #pragma unroll
    for (int off = 32; off; off >>= 1)
        #pragma unroll
        for (int e = 0; e < E; e++) acc[e] += __shfl_down(acc[e], off);

    if (lane == 0) {
        float s[E];
        #pragma unroll
        for (int e = 0; e < E; e++)
            s[e] = 1.0f / (1.0f + expf(-acc[e])) + bias[e];
        int i0 = 0;
        for (int e = 1; e < E; e++) if (s[e] > s[i0]) i0 = e;
        int i1 = -1;
        for (int e = 0; e < E; e++) {
            if (e == i0) continue;
            if (i1 < 0 || s[e] > s[i1]) i1 = e;
        }
        float m = fmaxf(s[i0], s[i1]);
        float w0 = expf(s[i0] - m), w1 = expf(s[i1] - m);
        float inv = 1.0f / (w0 + w1);
        se[2 * t] = i0;     sw[2 * t] = w0 * inv;
        se[2 * t + 1] = i1; sw[2 * t + 1] = w1 * inv;
    }
}

// ---------------- k1b: per-expert partition via block scan (1024 threads) ----------------
__global__ __launch_bounds__(1024) void k1b_partition(
    const int* __restrict__ se, int* __restrict__ token_list,
    int* __restrict__ sp, int* __restrict__ cnt) {
    int e = blockIdx.x;
    int tid = threadIdx.x;
    int wave = tid >> 6, lane = tid & 63;
    __shared__ int wsum[16];
    int running = 0;
    for (int c0 = 0; c0 < 2 * T; c0 += 1024) {
        int i = c0 + tid;
        bool pred = (se[i] == e);
        unsigned long long mask = __ballot(pred);
        int pos_in_wave = __popcll(mask & ((1ull << lane) - 1ull));
        if (lane == 0) wsum[wave] = __popcll(mask);
        __syncthreads();
        int wbase = 0;
        #pragma unroll
        for (int w2 = 0; w2 < 16; w2++) {
            int v = wsum[w2];
            if (w2 < wave) wbase += v;
        }
        int total = 0;
        #pragma unroll
        for (int w2 = 0; w2 < 16; w2++) total += wsum[w2];
        if (pred) {
            int p = running + wbase + pos_in_wave;
            token_list[e * T + p] = i >> 1;
            sp[i] = p;
        }
        running += total;
        __syncthreads();
    }
    if (tid == 0) cnt[e] = running;
}

// ---------------- k1.5: offsets + counts output + job table ----------------
__global__ void k15_offsets(const int* __restrict__ cnt, int* __restrict__ off,
                            float* __restrict__ out_counts,
                            int* __restrict__ jobs, int* __restrict__ njobs) {
    if (threadIdx.x == 0) {
        int acc = 0, nj = 0;
        for (int e = 0; e < E; e++) {
            off[e] = acc; acc += cnt[e];
            int mts = (cnt[e] + 127) >> 7;
            for (int mt = 0; mt < mts; mt++) jobs[nj++] = e * 64 + mt;
        }
        njobs[0] = nj;
    }
    if (threadIdx.x < E) out_counts[threadIdx.x] = (float)cnt[threadIdx.x];
}

// ---------------- k2: grouped GEMM gate+up (MFMA), BK=64, tile 128x128 dual ----------------
// A (tokens, bf16) staged via global_load_lds; B (gate/up weights) read as
// fp32 and converted to bf16 in-register during staging (saves the separate
// conversion pass: weights are consumed exactly once).
// Single-buffered, 48 KB LDS -> 3 blocks/CU; VGPR capped for 3 waves/EU.
__global__ __launch_bounds__(256, 3) void k2_gateup(
    const __bf16* __restrict__ xb, const float* __restrict__ gw,
    const float* __restrict__ uw, const int* __restrict__ cnt,
    const int* __restrict__ off, const int* __restrict__ token_list,
    const int* __restrict__ jobs, const int* __restrict__ njobs,
    __bf16* __restrict__ h) {
    int jt = blockIdx.x >> 4, nt = blockIdx.x & 15;   // nt: 0..15 (DFF/128)
    if (jt >= njobs[0]) return;
    int job = jobs[jt];
    int e = job >> 6, mt = job & 63;
    int Me = cnt[e], offe = off[e];

    __shared__ __bf16 As[128 * 64];   // 16 KB
    __shared__ __bf16 Bg[128 * 64];   // 16 KB
    __shared__ __bf16 Bu[128 * 64];   // 16 KB

    int tid = threadIdx.x;
    int lane = tid & 63, w = tid >> 6;
    int wm = w >> 1, wn = w & 1;

    // staging sources: LDS slot (row, l&7) receives global k-chunk (l&7)^(row&7)
    const __bf16* asrc[4];
    const float4 *pg[4], *pu[4];
    #pragma unroll
    for (int rr = 0; rr < 4; rr++) {
        int l = rr * 256 + tid;
        int row = l >> 3, sl = l & 7;
        int ch = sl ^ (row & 7);
        int gr = mt * 128 + row; if (gr >= Me) gr = Me - 1;
        int tok = token_list[e * T + gr];
        asrc[rr] = xb + (size_t)tok * H + ch * 8;
        size_t fbase = ((size_t)e * DFF + nt * 128 + row) * H + ch * 8;
        pg[rr] = (const float4*)(gw + fbase);
        pu[rr] = (const float4*)(uw + fbase);
    }

    f32x4 accg[4][4] = {};
    f32x4 accu[4][4] = {};
    int kq = lane >> 4, m15 = lane & 15;

    for (int k0 = 0; k0 < H; k0 += 64) {
        int k4 = k0 >> 2;
        #pragma unroll
        for (int rr = 0; rr < 4; rr++)
            gload16(asrc[rr] + k0, &As[(rr * 256 + tid) * 8]);
        #pragma unroll
        for (int rr = 0; rr < 4; rr++) {
            float4 g0 = pg[rr][k4], g1 = pg[rr][k4 + 1];
            float4 u0 = pu[rr][k4], u1 = pu[rr][k4 + 1];
            bf16x8 gv = {(__bf16)g0.x, (__bf16)g0.y, (__bf16)g0.z, (__bf16)g0.w,
                         (__bf16)g1.x, (__bf16)g1.y, (__bf16)g1.z, (__bf16)g1.w};
            bf16x8 uv = {(__bf16)u0.x, (__bf16)u0.y, (__bf16)u0.z, (__bf16)u0.w,
                         (__bf16)u1.x, (__bf16)u1.y, (__bf16)u1.z, (__bf16)u1.w};
            *(bf16x8*)&Bg[(rr * 256 + tid) * 8] = gv;
            *(bf16x8*)&Bu[(rr * 256 + tid) * 8] = uv;
        }
        __syncthreads();

        #pragma unroll
        for (int kc = 0; kc < 2; kc++) {
            bf16x8 af[4], gf[4], uf[4];
            #pragma unroll
            for (int i = 0; i < 4; i++) {
                int row = wm * 64 + i * 16 + m15;
                int sl = (kc * 4 + kq) ^ (row & 7);
                af[i] = *(const bf16x8*)&As[row * 64 + sl * 8];
            }
            #pragma unroll
            for (int j = 0; j < 4; j++) {
                int row = wn * 64 + j * 16 + m15;
                int sl = (kc * 4 + kq) ^ (row & 7);
                gf[j] = *(const bf16x8*)&Bg[row * 64 + sl * 8];
                uf[j] = *(const bf16x8*)&Bu[row * 64 + sl * 8];
            }
            #pragma unroll
            for (int i = 0; i < 4; i++)
                #pragma unroll
                for (int j = 0; j < 4; j++) {
                    accg[i][j] = __builtin_amdgcn_mfma_f32_16x16x32_bf16(af[i], gf[j], accg[i][j], 0, 0, 0);
                    accu[i][j] = __builtin_amdgcn_mfma_f32_16x16x32_bf16(af[i], uf[j], accu[i][j], 0, 0, 0);
                }
        }
        __syncthreads();
    }

    // epilogue: h = silu(g) * u
    #pragma unroll
    for (int i = 0; i < 4; i++)
        #pragma unroll
        for (int j = 0; j < 4; j++) {
            int nloc = wn * 64 + j * 16 + m15;
            size_t c = (size_t)nt * 128 + nloc;
            #pragma unroll
            for (int p = 0; p < 4; p++) {
                int mloc = wm * 64 + i * 16 + kq * 4 + p;
                int mrow = mt * 128 + mloc;
                if (mrow < Me) {
                    float g = accg[i][j][p], u = accu[i][j][p];
                    float sig = 1.0f / (1.0f + __expf(-g));
                    h[(size_t)(offe + mrow) * DFF + c] = (__bf16)(g * sig * u);
                }
            }
        }
}

// ---------------- k3: grouped GEMM down (MFMA), BK=64, tile 128x128 ----------------
// A (h, bf16) via global_load_lds; B (down weights) fp32 -> bf16 in staging.
__global__ __launch_bounds__(256, 3) void k3_down(
    const __bf16* __restrict__ h, const float* __restrict__ dw,
    const int* __restrict__ cnt, const int* __restrict__ off,
    const int* __restrict__ jobs, const int* __restrict__ njobs,
    __bf16* __restrict__ y) {
    int jt = blockIdx.x >> 3, nt = blockIdx.x & 7;    // nt: 0..7 (H/128)
    if (jt >= njobs[0]) return;
    int job = jobs[jt];
    int e = job >> 6, mt = job & 63;
    int Me = cnt[e], offe = off[e];

    __shared__ __bf16 As[128 * 64];   // 16 KB
    __shared__ __bf16 Bs[128 * 64];   // 16 KB

    int tid = threadIdx.x;
    int lane = tid & 63, w = tid >> 6;
    int wm = w >> 1, wn = w & 1;

    const __bf16* asrc[4];
    const float4* pb[4];
    #pragma unroll
    for (int rr = 0; rr < 4; rr++) {
        int l = rr * 256 + tid;
        int row = l >> 3, sl = l & 7;
        int ch = sl ^ (row & 7);
        int gr = mt * 128 + row; if (gr >= Me) gr = Me - 1;
        asrc[rr] = h + (size_t)(offe + gr) * DFF + ch * 8;
        pb[rr] = (const float4*)(dw + ((size_t)e * H + nt * 128 + row) * DFF + ch * 8);
    }

    f32x4 acc[4][4] = {};
    int kq = lane >> 4, m15 = lane & 15;

    for (int k0 = 0; k0 < DFF; k0 += 64) {
        int k4 = k0 >> 2;
        #pragma unroll
        for (int rr = 0; rr < 4; rr++)
            gload16(asrc[rr] + k0, &As[(rr * 256 + tid) * 8]);
        #pragma unroll
        for (int rr = 0; rr < 4; rr++) {
            float4 b0 = pb[rr][k4], b1 = pb[rr][k4 + 1];
            bf16x8 bv = {(__bf16)b0.x, (__bf16)b0.y, (__bf16)b0.z, (__bf16)b0.w,
                         (__bf16)b1.x, (__bf16)b1.y, (__bf16)b1.z, (__bf16)b1.w};
            *(bf16x8*)&Bs[(rr * 256 + tid) * 8] = bv;
        }
        __syncthreads();

        #pragma unroll
        for (int kc = 0; kc < 2; kc++) {
            bf16x8 af[4], bfr[4];
            #pragma unroll
            for (int i = 0; i < 4; i++) {
                int row = wm * 64 + i * 16 + m15;
                int sl = (kc * 4 + kq) ^ (row & 7);
                af[i] = *(const bf16x8*)&As[row * 64 + sl * 8];
            }
            #pragma unroll
            for (int j = 0; j < 4; j++) {
                int row = wn * 64 + j * 16 + m15;
                int sl = (kc * 4 + kq) ^ (row & 7);
                bfr[j] = *(const bf16x8*)&Bs[row * 64 + sl * 8];
            }
            #pragma unroll
            for (int i = 0; i < 4; i++)
                #pragma unroll
                for (int j = 0; j < 4; j++)
                    acc[i][j] = __builtin_amdgcn_mfma_f32_16x16x32_bf16(af[i], bfr[j], acc[i][j], 0, 0, 0);
        }
        __syncthreads();
    }

    #pragma unroll
    for (int i = 0; i < 4; i++)
        #pragma unroll
        for (int j = 0; j < 4; j++) {
            int nglob = nt * 128 + wn * 64 + j * 16 + m15;
            #pragma unroll
            for (int p = 0; p < 4; p++) {
                int mloc = wm * 64 + i * 16 + kq * 4 + p;
                int mrow = mt * 128 + mloc;
                if (mrow < Me)
                    y[(size_t)(offe + mrow) * H + nglob] = (__bf16)acc[i][j][p];
            }
        }
}

// ---------------- gather: weighted top-2 combine -> out ----------------
__global__ __launch_bounds__(256) void k_gather(
    const __bf16* __restrict__ y, const int* __restrict__ se,
    const int* __restrict__ sp, const float* __restrict__ sw,
    const int* __restrict__ off, float* __restrict__ out) {
    int t = blockIdx.x;
    int r0 = off[se[2 * t]] + sp[2 * t];
    int r1 = off[se[2 * t + 1]] + sp[2 * t + 1];
    float w0 = sw[2 * t], w1 = sw[2 * t + 1];
    const bf16x4* y0 = (const bf16x4*)(y + (size_t)r0 * H);
    const bf16x4* y1 = (const bf16x4*)(y + (size_t)r1 * H);
    float4* o = (float4*)(out + (size_t)t * H);
    int c = threadIdx.x;
    bf16x4 a = y0[c], b = y1[c];
    float4 v;
    v.x = w0 * (float)a[0] + w1 * (float)b[0];
    v.y = w0 * (float)a[1] + w1 * (float)b[1];
    v.z = w0 * (float)a[2] + w1 * (float)b[2];
    v.w = w0 * (float)a[3] + w1 * (float)b[3];
    o[c] = v;
}

// ---------------- launch ----------------
extern "C" void kernel_launch(void* const* d_in, const int* in_sizes, int n_in,
                              void* d_out, int out_size, void* d_ws, size_t ws_size,
                              hipStream_t stream) {
    const float* x    = (const float*)d_in[0];
    const float* cent = (const float*)d_in[1];
    const float* gw   = (const float*)d_in[2];
    const float* uw   = (const float*)d_in[3];
    const float* dw   = (const float*)d_in[4];
    const float* bias = (const float*)d_in[5];
    float* out = (float*)d_out;

    // workspace layout (bytes)
    char* ws = (char*)d_ws;
    int*   cnt        = (int*)(ws + 0);
    int*   off        = (int*)(ws + 64);
    int*   se         = (int*)(ws + 128);              // 32 KB
    int*   sp         = (int*)(ws + 128 + 32768);      // 32 KB
    float* sw         = (float*)(ws + 128 + 65536);    // 32 KB
    int*   token_list = (int*)(ws + 128 + 98304);      // 128 KB
    int*   jobs       = (int*)(ws + 229504);           // 80 ints
    int*   njobs      = (int*)(ws + 229824);           // 1 int
    const size_t MB = 1u << 20;
    __bf16* xb = (__bf16*)(ws + 1 * MB);               // 8 MB
    __bf16* h  = (__bf16*)(ws + 1 * MB + 8388608);     // 32 MB
    __bf16* y  = (__bf16*)(ws + 1 * MB + 41943040);    // 16 MB

    const int X4 = T * H / 4;

    k0_fused<<<1024 + (X4 + 255) / 256, 256, 0, stream>>>(
        x, cent, bias, se, sw, xb, X4);
    k1b_partition<<<E, 1024, 0, stream>>>(se, token_list, sp, cnt);
    k15_offsets<<<1, 64, 0, stream>>>(cnt, off, out + (size_t)T * H, jobs, njobs);
    k2_gateup<<<MAXJ * 16, 256, 0, stream>>>(xb, gw, uw, cnt, off, token_list, jobs, njobs, h);
    k3_down<<<MAXJ * 8, 256, 0, stream>>>(h, dw, cnt, off, jobs, njobs, y);
    k_gather<<<T, 256, 0, stream>>>(y, se, sp, sw, off, out);
}

// Round 4
// 418.713 us; speedup vs baseline: 1.4290x; 1.4290x over previous
//
#include <hip/hip_runtime.h>
#include <math.h>

// Problem constants
constexpr int E = 8, H = 1024, DFF = 2048, T = 4096;
constexpr int TR = 8192;          // total routed rows = T * topk
constexpr int MAXJ = 72;          // max (expert, m-tile) jobs: 8192/128 + E

typedef __bf16 bf16x8 __attribute__((ext_vector_type(8)));
typedef __bf16 bf16x4 __attribute__((ext_vector_type(4)));
typedef float f32x4 __attribute__((ext_vector_type(4)));

__device__ __forceinline__ void gload16(const void* g, void* l) {
    __builtin_amdgcn_global_load_lds(
        (const __attribute__((address_space(1))) unsigned int*)g,
        (__attribute__((address_space(3))) unsigned int*)l, 16, 0, 0);
}

// ---------------- k0: fused x->bf16 conversion + affinity/top-2 ----------------
// blocks [0,1024): affinity; blocks [1024, 1024+4096): x fp32->bf16.
__global__ __launch_bounds__(256) void k0_fused(
    const float* __restrict__ x, const float* __restrict__ cent,
    const float* __restrict__ bias,
    int* __restrict__ se, float* __restrict__ sw,
    __bf16* __restrict__ xb, int x4) {
    __shared__ float cs[E * H];
    int tid = threadIdx.x;

    if (blockIdx.x >= 1024) {
        int i = (blockIdx.x - 1024) * 256 + tid;
        if (i < x4) {
            float4 v = ((const float4*)x)[i];
            bf16x4 o = {(__bf16)v.x, (__bf16)v.y, (__bf16)v.z, (__bf16)v.w};
            ((bf16x4*)xb)[i] = o;
        }
        return;
    }

    // affinity role
    for (int i = tid; i < E * H / 4; i += 256)
        ((float4*)cs)[i] = ((const float4*)cent)[i];
    __syncthreads();

    int wave = tid >> 6, lane = tid & 63;
    int t = blockIdx.x * 4 + wave;
    const float4* xr = (const float4*)(x + (size_t)t * H);
    float acc[E] = {};
    #pragma unroll
    for (int it = 0; it < 4; it++) {
        float4 xv = xr[lane + it * 64];
        #pragma unroll
        for (int e = 0; e < E; e++) {
            float4 cv = ((const float4*)(cs + e * H))[lane + it * 64];
            acc[e] = fmaf(xv.x, cv.x, acc[e]);
            acc[e] = fmaf(xv.y, cv.y, acc[e]);
            acc[e] = fmaf(xv.z, cv.z, acc[e]);
            acc[e] = fmaf(xv.w, cv.w, acc[e]);
        }
    }
    #pragma unroll
    for (int off = 32; off; off >>= 1)
        #pragma unroll
        for (int e = 0; e < E; e++) acc[e] += __shfl_down(acc[e], off);

    if (lane == 0) {
        float s[E];
        #pragma unroll
        for (int e = 0; e < E; e++)
            s[e] = 1.0f / (1.0f + expf(-acc[e])) + bias[e];
        int i0 = 0;
        for (int e = 1; e < E; e++) if (s[e] > s[i0]) i0 = e;
        int i1 = -1;
        for (int e = 0; e < E; e++) {
            if (e == i0) continue;
            if (i1 < 0 || s[e] > s[i1]) i1 = e;
        }
        float m = fmaxf(s[i0], s[i1]);
        float w0 = expf(s[i0] - m), w1 = expf(s[i1] - m);
        float inv = 1.0f / (w0 + w1);
        se[2 * t] = i0;     sw[2 * t] = w0 * inv;
        se[2 * t + 1] = i1; sw[2 * t + 1] = w1 * inv;
    }
}

// ---------------- k1b: per-expert partition via block scan (1024 threads) ----------------
__global__ __launch_bounds__(1024) void k1b_partition(
    const int* __restrict__ se, int* __restrict__ token_list,
    int* __restrict__ sp, int* __restrict__ cnt) {
    int e = blockIdx.x;
    int tid = threadIdx.x;
    int wave = tid >> 6, lane = tid & 63;
    __shared__ int wsum[16];
    int running = 0;
    for (int c0 = 0; c0 < 2 * T; c0 += 1024) {
        int i = c0 + tid;
        bool pred = (se[i] == e);
        unsigned long long mask = __ballot(pred);
        int pos_in_wave = __popcll(mask & ((1ull << lane) - 1ull));
        if (lane == 0) wsum[wave] = __popcll(mask);
        __syncthreads();
        int wbase = 0;
        #pragma unroll
        for (int w2 = 0; w2 < 16; w2++) {
            int v = wsum[w2];
            if (w2 < wave) wbase += v;
        }
        int total = 0;
        #pragma unroll
        for (int w2 = 0; w2 < 16; w2++) total += wsum[w2];
        if (pred) {
            int p = running + wbase + pos_in_wave;
            token_list[e * T + p] = i >> 1;
            sp[i] = p;
        }
        running += total;
        __syncthreads();
    }
    if (tid == 0) cnt[e] = running;
}

// ---------------- k1.5: offsets + counts output + job table ----------------
__global__ void k15_offsets(const int* __restrict__ cnt, int* __restrict__ off,
                            float* __restrict__ out_counts,
                            int* __restrict__ jobs, int* __restrict__ njobs) {
    if (threadIdx.x == 0) {
        int acc = 0, nj = 0;
        for (int e = 0; e < E; e++) {
            off[e] = acc; acc += cnt[e];
            int mts = (cnt[e] + 127) >> 7;
            for (int mt = 0; mt < mts; mt++) jobs[nj++] = e * 64 + mt;
        }
        njobs[0] = nj;
    }
    if (threadIdx.x < E) out_counts[threadIdx.x] = (float)cnt[threadIdx.x];
}

// ---------------- k2: grouped GEMM gate+up (MFMA), BK=64, tile 128x128 dual ----------------
// A (tokens, bf16) staged via global_load_lds; B (gate/up weights) read as
// fp32 and converted to bf16 in-register during staging. Gate and up halves
// staged sequentially (sched_barrier between) to halve peak VGPR pressure.
// Single-buffered, 48 KB LDS; NO aggressive min-waves bound (round-3 spill).
__global__ __launch_bounds__(256, 2) void k2_gateup(
    const __bf16* __restrict__ xb, const float* __restrict__ gw,
    const float* __restrict__ uw, const int* __restrict__ cnt,
    const int* __restrict__ off, const int* __restrict__ token_list,
    const int* __restrict__ jobs, const int* __restrict__ njobs,
    __bf16* __restrict__ h) {
    int jt = blockIdx.x >> 4, nt = blockIdx.x & 15;   // nt: 0..15 (DFF/128)
    if (jt >= njobs[0]) return;
    int job = jobs[jt];
    int e = job >> 6, mt = job & 63;
    int Me = cnt[e], offe = off[e];

    __shared__ __bf16 As[128 * 64];   // 16 KB
    __shared__ __bf16 Bg[128 * 64];   // 16 KB
    __shared__ __bf16 Bu[128 * 64];   // 16 KB

    int tid = threadIdx.x;
    int lane = tid & 63, w = tid >> 6;
    int wm = w >> 1, wn = w & 1;

    // staging sources: LDS slot (row, l&7) receives global k-chunk (l&7)^(row&7)
    const __bf16* asrc[4];
    const float4 *pg[4], *pu[4];
    #pragma unroll
    for (int rr = 0; rr < 4; rr++) {
        int l = rr * 256 + tid;
        int row = l >> 3, sl = l & 7;
        int ch = sl ^ (row & 7);
        int gr = mt * 128 + row; if (gr >= Me) gr = Me - 1;
        int tok = token_list[e * T + gr];
        asrc[rr] = xb + (size_t)tok * H + ch * 8;
        size_t fbase = ((size_t)e * DFF + nt * 128 + row) * H + ch * 8;
        pg[rr] = (const float4*)(gw + fbase);
        pu[rr] = (const float4*)(uw + fbase);
    }

    f32x4 accg[4][4] = {};
    f32x4 accu[4][4] = {};
    int kq = lane >> 4, m15 = lane & 15;

    for (int k0 = 0; k0 < H; k0 += 64) {
        int k4 = k0 >> 2;
        #pragma unroll
        for (int rr = 0; rr < 4; rr++)
            gload16(asrc[rr] + k0, &As[(rr * 256 + tid) * 8]);
        // gate half
        #pragma unroll
        for (int rr = 0; rr < 4; rr++) {
            float4 g0 = pg[rr][k4], g1 = pg[rr][k4 + 1];
            bf16x8 gv = {(__bf16)g0.x, (__bf16)g0.y, (__bf16)g0.z, (__bf16)g0.w,
                         (__bf16)g1.x, (__bf16)g1.y, (__bf16)g1.z, (__bf16)g1.w};
            *(bf16x8*)&Bg[(rr * 256 + tid) * 8] = gv;
        }
        __builtin_amdgcn_sched_barrier(0);   // keep up-half loads from hoisting: caps live regs
        // up half
        #pragma unroll
        for (int rr = 0; rr < 4; rr++) {
            float4 u0 = pu[rr][k4], u1 = pu[rr][k4 + 1];
            bf16x8 uv = {(__bf16)u0.x, (__bf16)u0.y, (__bf16)u0.z, (__bf16)u0.w,
                         (__bf16)u1.x, (__bf16)u1.y, (__bf16)u1.z, (__bf16)u1.w};
            *(bf16x8*)&Bu[(rr * 256 + tid) * 8] = uv;
        }
        __syncthreads();

        #pragma unroll
        for (int kc = 0; kc < 2; kc++) {
            bf16x8 af[4], gf[4], uf[4];
            #pragma unroll
            for (int i = 0; i < 4; i++) {
                int row = wm * 64 + i * 16 + m15;
                int sl = (kc * 4 + kq) ^ (row & 7);
                af[i] = *(const bf16x8*)&As[row * 64 + sl * 8];
            }
            #pragma unroll
            for (int j = 0; j < 4; j++) {
                int row = wn * 64 + j * 16 + m15;
                int sl = (kc * 4 + kq) ^ (row & 7);
                gf[j] = *(const bf16x8*)&Bg[row * 64 + sl * 8];
                uf[j] = *(const bf16x8*)&Bu[row * 64 + sl * 8];
            }
            #pragma unroll
            for (int i = 0; i < 4; i++)
                #pragma unroll
                for (int j = 0; j < 4; j++) {
                    accg[i][j] = __builtin_amdgcn_mfma_f32_16x16x32_bf16(af[i], gf[j], accg[i][j], 0, 0, 0);
                    accu[i][j] = __builtin_amdgcn_mfma_f32_16x16x32_bf16(af[i], uf[j], accu[i][j], 0, 0, 0);
                }
        }
        __syncthreads();
    }

    // epilogue: h = silu(g) * u
    #pragma unroll
    for (int i = 0; i < 4; i++)
        #pragma unroll
        for (int j = 0; j < 4; j++) {
            int nloc = wn * 64 + j * 16 + m15;
            size_t c = (size_t)nt * 128 + nloc;
            #pragma unroll
            for (int p = 0; p < 4; p++) {
                int mloc = wm * 64 + i * 16 + kq * 4 + p;
                int mrow = mt * 128 + mloc;
                if (mrow < Me) {
                    float g = accg[i][j][p], u = accu[i][j][p];
                    float sig = 1.0f / (1.0f + __expf(-g));
                    h[(size_t)(offe + mrow) * DFF + c] = (__bf16)(g * sig * u);
                }
            }
        }
}

// ---------------- k3: grouped GEMM down (MFMA), BK=64, tile 128x128 ----------------
// A (h, bf16) via global_load_lds; B (down weights) fp32 -> bf16 in staging.
__global__ __launch_bounds__(256, 2) void k3_down(
    const __bf16* __restrict__ h, const float* __restrict__ dw,
    const int* __restrict__ cnt, const int* __restrict__ off,
    const int* __restrict__ jobs, const int* __restrict__ njobs,
    __bf16* __restrict__ y) {
    int jt = blockIdx.x >> 3, nt = blockIdx.x & 7;    // nt: 0..7 (H/128)
    if (jt >= njobs[0]) return;
    int job = jobs[jt];
    int e = job >> 6, mt = job & 63;
    int Me = cnt[e], offe = off[e];

    __shared__ __bf16 As[128 * 64];   // 16 KB
    __shared__ __bf16 Bs[128 * 64];   // 16 KB

    int tid = threadIdx.x;
    int lane = tid & 63, w = tid >> 6;
    int wm = w >> 1, wn = w & 1;

    const __bf16* asrc[4];
    const float4* pb[4];
    #pragma unroll
    for (int rr = 0; rr < 4; rr++) {
        int l = rr * 256 + tid;
        int row = l >> 3, sl = l & 7;
        int ch = sl ^ (row & 7);
        int gr = mt * 128 + row; if (gr >= Me) gr = Me - 1;
        asrc[rr] = h + (size_t)(offe + gr) * DFF + ch * 8;
        pb[rr] = (const float4*)(dw + ((size_t)e * H + nt * 128 + row) * DFF + ch * 8);
    }

    f32x4 acc[4][4] = {};
    int kq = lane >> 4, m15 = lane & 15;

    for (int k0 = 0; k0 < DFF; k0 += 64) {
        int k4 = k0 >> 2;
        #pragma unroll
        for (int rr = 0; rr < 4; rr++)
            gload16(asrc[rr] + k0, &As[(rr * 256 + tid) * 8]);
        #pragma unroll
        for (int rr = 0; rr < 4; rr++) {
            float4 b0 = pb[rr][k4], b1 = pb[rr][k4 + 1];
            bf16x8 bv = {(__bf16)b0.x, (__bf16)b0.y, (__bf16)b0.z, (__bf16)b0.w,
                         (__bf16)b1.x, (__bf16)b1.y, (__bf16)b1.z, (__bf16)b1.w};
            *(bf16x8*)&Bs[(rr * 256 + tid) * 8] = bv;
        }
        __syncthreads();

        #pragma unroll
        for (int kc = 0; kc < 2; kc++) {
            bf16x8 af[4], bfr[4];
            #pragma unroll
            for (int i = 0; i < 4; i++) {
                int row = wm * 64 + i * 16 + m15;
                int sl = (kc * 4 + kq) ^ (row & 7);
                af[i] = *(const bf16x8*)&As[row * 64 + sl * 8];
            }
            #pragma unroll
            for (int j = 0; j < 4; j++) {
                int row = wn * 64 + j * 16 + m15;
                int sl = (kc * 4 + kq) ^ (row & 7);
                bfr[j] = *(const bf16x8*)&Bs[row * 64 + sl * 8];
            }
            #pragma unroll
            for (int i = 0; i < 4; i++)
                #pragma unroll
                for (int j = 0; j < 4; j++)
                    acc[i][j] = __builtin_amdgcn_mfma_f32_16x16x32_bf16(af[i], bfr[j], acc[i][j], 0, 0, 0);
        }
        __syncthreads();
    }

    #pragma unroll
    for (int i = 0; i < 4; i++)
        #pragma unroll
        for (int j = 0; j < 4; j++) {
            int nglob = nt * 128 + wn * 64 + j * 16 + m15;
            #pragma unroll
            for (int p = 0; p < 4; p++) {
                int mloc = wm * 64 + i * 16 + kq * 4 + p;
                int mrow = mt * 128 + mloc;
                if (mrow < Me)
                    y[(size_t)(offe + mrow) * H + nglob] = (__bf16)acc[i][j][p];
            }
        }
}

// ---------------- gather: weighted top-2 combine -> out ----------------
__global__ __launch_bounds__(256) void k_gather(
    const __bf16* __restrict__ y, const int* __restrict__ se,
    const int* __restrict__ sp, const float* __restrict__ sw,
    const int* __restrict__ off, float* __restrict__ out) {
    int t = blockIdx.x;
    int r0 = off[se[2 * t]] + sp[2 * t];
    int r1 = off[se[2 * t + 1]] + sp[2 * t + 1];
    float w0 = sw[2 * t], w1 = sw[2 * t + 1];
    const bf16x4* y0 = (const bf16x4*)(y + (size_t)r0 * H);
    const bf16x4* y1 = (const bf16x4*)(y + (size_t)r1 * H);
    float4* o = (float4*)(out + (size_t)t * H);
    int c = threadIdx.x;
    bf16x4 a = y0[c], b = y1[c];
    float4 v;
    v.x = w0 * (float)a[0] + w1 * (float)b[0];
    v.y = w0 * (float)a[1] + w1 * (float)b[1];
    v.z = w0 * (float)a[2] + w1 * (float)b[2];
    v.w = w0 * (float)a[3] + w1 * (float)b[3];
    o[c] = v;
}

// ---------------- launch ----------------
extern "C" void kernel_launch(void* const* d_in, const int* in_sizes, int n_in,
                              void* d_out, int out_size, void* d_ws, size_t ws_size,
                              hipStream_t stream) {
    const float* x    = (const float*)d_in[0];
    const float* cent = (const float*)d_in[1];
    const float* gw   = (const float*)d_in[2];
    const float* uw   = (const float*)d_in[3];
    const float* dw   = (const float*)d_in[4];
    const float* bias = (const float*)d_in[5];
    float* out = (float*)d_out;

    // workspace layout (bytes)
    char* ws = (char*)d_ws;
    int*   cnt        = (int*)(ws + 0);
    int*   off        = (int*)(ws + 64);
    int*   se         = (int*)(ws + 128);              // 32 KB
    int*   sp         = (int*)(ws + 128 + 32768);      // 32 KB
    float* sw         = (float*)(ws + 128 + 65536);    // 32 KB
    int*   token_list = (int*)(ws + 128 + 98304);      // 128 KB
    int*   jobs       = (int*)(ws + 229504);           // 80 ints
    int*   njobs      = (int*)(ws + 229824);           // 1 int
    const size_t MB = 1u << 20;
    __bf16* xb = (__bf16*)(ws + 1 * MB);               // 8 MB
    __bf16* h  = (__bf16*)(ws + 1 * MB + 8388608);     // 32 MB
    __bf16* y  = (__bf16*)(ws + 1 * MB + 41943040);    // 16 MB

    const int X4 = T * H / 4;

    k0_fused<<<1024 + (X4 + 255) / 256, 256, 0, stream>>>(
        x, cent, bias, se, sw, xb, X4);
    k1b_partition<<<E, 1024, 0, stream>>>(se, token_list, sp, cnt);
    k15_offsets<<<1, 64, 0, stream>>>(cnt, off, out + (size_t)T * H, jobs, njobs);
    k2_gateup<<<MAXJ * 16, 256, 0, stream>>>(xb, gw, uw, cnt, off, token_list, jobs, njobs, h);
    k3_down<<<MAXJ * 8, 256, 0, stream>>>(h, dw, cnt, off, jobs, njobs, y);
    k_gather<<<T, 256, 0, stream>>>(y, se, sp, sw, off, out);
}

// Round 5
// 401.057 us; speedup vs baseline: 1.4919x; 1.0440x over previous
//
#include <hip/hip_runtime.h>
#include <math.h>

// Problem constants
constexpr int E = 8, H = 1024, DFF = 2048, T = 4096;
constexpr int TR = 8192;          // total routed rows = T * topk
constexpr int MAXJ = 72;          // max (expert, m-tile) jobs: 8192/128 + E

typedef __bf16 bf16x8 __attribute__((ext_vector_type(8)));
typedef __bf16 bf16x4 __attribute__((ext_vector_type(4)));
typedef float f32x4 __attribute__((ext_vector_type(4)));

__device__ __forceinline__ void gload16(const void* g, void* l) {
    __builtin_amdgcn_global_load_lds(
        (const __attribute__((address_space(1))) unsigned int*)g,
        (__attribute__((address_space(3))) unsigned int*)l, 16, 0, 0);
}

// ---------------- k0: fused conversions (gw,uw[,dw],x -> bf16) + affinity/top-2 ----------------
// blocks [0,1024): affinity; blocks [1024, ...): fp32->bf16 conversion stream.
__global__ __launch_bounds__(256) void k0_fused(
    const float* __restrict__ x, const float* __restrict__ cent,
    const float* __restrict__ bias,
    int* __restrict__ se, float* __restrict__ sw,
    const float* __restrict__ gw, __bf16* __restrict__ gwb,
    const float* __restrict__ uw, __bf16* __restrict__ uwb,
    const float* __restrict__ dw, __bf16* __restrict__ dwb,   // dw may be null
    __bf16* __restrict__ xb, int w4, int x4, int* __restrict__ done) {
    __shared__ float cs[E * H];
    int tid = threadIdx.x;

    if (blockIdx.x == 0 && tid == 0) *done = 0;   // reset for k1b's last-block pattern

    if (blockIdx.x >= 1024) {
        // conversion role
        int i = (blockIdx.x - 1024) * 256 + tid;
        const float* in; __bf16* outp; int idx;
        if (i < w4) { in = gw; outp = gwb; idx = i; }
        else if (i < 2 * w4) { in = uw; outp = uwb; idx = i - w4; }
        else if (dw != nullptr && i < 3 * w4) { in = dw; outp = dwb; idx = i - 2 * w4; }
        else {
            int base = (dw != nullptr) ? 3 * w4 : 2 * w4;
            idx = i - base; if (idx >= x4) return; in = x; outp = xb;
        }
        float4 v = ((const float4*)in)[idx];
        bf16x4 o = {(__bf16)v.x, (__bf16)v.y, (__bf16)v.z, (__bf16)v.w};
        ((bf16x4*)outp)[idx] = o;
        return;
    }

    // affinity role
    for (int i = tid; i < E * H / 4; i += 256)
        ((float4*)cs)[i] = ((const float4*)cent)[i];
    __syncthreads();

    int wave = tid >> 6, lane = tid & 63;
    int t = blockIdx.x * 4 + wave;
    const float4* xr = (const float4*)(x + (size_t)t * H);
    float acc[E] = {};
    #pragma unroll
    for (int it = 0; it < 4; it++) {
        float4 xv = xr[lane + it * 64];
        #pragma unroll
        for (int e = 0; e < E; e++) {
            float4 cv = ((const float4*)(cs + e * H))[lane + it * 64];
            acc[e] = fmaf(xv.x, cv.x, acc[e]);
            acc[e] = fmaf(xv.y, cv.y, acc[e]);
            acc[e] = fmaf(xv.z, cv.z, acc[e]);
            acc[e] = fmaf(xv.w, cv.w, acc[e]);
        }
    }
    #pragma unroll
    for (int off = 32; off; off >>= 1)
        #pragma unroll
        for (int e = 0; e < E; e++) acc[e] += __shfl_down(acc[e], off);

    if (lane == 0) {
        float s[E];
        #pragma unroll
        for (int e = 0; e < E; e++)
            s[e] = 1.0f / (1.0f + expf(-acc[e])) + bias[e];
        int i0 = 0;
        for (int e = 1; e < E; e++) if (s[e] > s[i0]) i0 = e;
        int i1 = -1;
        for (int e = 0; e < E; e++) {
            if (e == i0) continue;
            if (i1 < 0 || s[e] > s[i1]) i1 = e;
        }
        float m = fmaxf(s[i0], s[i1]);
        float w0 = expf(s[i0] - m), w1 = expf(s[i1] - m);
        float inv = 1.0f / (w0 + w1);
        se[2 * t] = i0;     sw[2 * t] = w0 * inv;
        se[2 * t + 1] = i1; sw[2 * t + 1] = w1 * inv;
    }
}

// ---------------- k1b: per-expert partition + (last block) offsets/jobs ----------------
__global__ __launch_bounds__(1024) void k1b_partition(
    const int* __restrict__ se, int* __restrict__ token_list,
    int* __restrict__ sp, int* __restrict__ cnt,
    int* __restrict__ off, float* __restrict__ out_counts,
    int* __restrict__ jobs, int* __restrict__ njobs, int* __restrict__ done) {
    int e = blockIdx.x;
    int tid = threadIdx.x;
    int wave = tid >> 6, lane = tid & 63;
    __shared__ int wsum[16];
    int running = 0;
    for (int c0 = 0; c0 < 2 * T; c0 += 1024) {
        int i = c0 + tid;
        bool pred = (se[i] == e);
        unsigned long long mask = __ballot(pred);
        int pos_in_wave = __popcll(mask & ((1ull << lane) - 1ull));
        if (lane == 0) wsum[wave] = __popcll(mask);
        __syncthreads();
        int wbase = 0;
        #pragma unroll
        for (int w2 = 0; w2 < 16; w2++) {
            int v = wsum[w2];
            if (w2 < wave) wbase += v;
        }
        int total = 0;
        #pragma unroll
        for (int w2 = 0; w2 < 16; w2++) total += wsum[w2];
        if (pred) {
            int p = running + wbase + pos_in_wave;
            token_list[e * T + p] = i >> 1;
            sp[i] = p;
        }
        running += total;
        __syncthreads();
    }
    if (tid == 0) {
        __hip_atomic_store(&cnt[e], running, __ATOMIC_RELEASE, __HIP_MEMORY_SCOPE_AGENT);
        int prev = __hip_atomic_fetch_add(done, 1, __ATOMIC_ACQ_REL, __HIP_MEMORY_SCOPE_AGENT);
        if (prev == E - 1) {
            // last block to finish: compute offsets + job table + counts output
            int acc = 0, nj = 0;
            for (int e2 = 0; e2 < E; e2++) {
                int c = __hip_atomic_load(&cnt[e2], __ATOMIC_ACQUIRE, __HIP_MEMORY_SCOPE_AGENT);
                off[e2] = acc; acc += c;
                out_counts[e2] = (float)c;
                int mts = (c + 127) >> 7;
                for (int mt = 0; mt < mts; mt++) jobs[nj++] = e2 * 64 + mt;
            }
            njobs[0] = nj;
        }
    }
}

// ---------------- conv: fp32 -> bf16 (single tensor; fallback path only) ----------------
__global__ __launch_bounds__(256) void k_conv(const float* __restrict__ in,
                                              __bf16* __restrict__ out, int n4) {
    int i = blockIdx.x * 256 + threadIdx.x;
    if (i < n4) {
        float4 v = ((const float4*)in)[i];
        bf16x4 o = {(__bf16)v.x, (__bf16)v.y, (__bf16)v.z, (__bf16)v.w};
        ((bf16x4*)out)[i] = o;
    }
}

// ---------------- k2: grouped GEMM gate+up (MFMA), BK=64, tile 128x128 dual ----------------
// 4 waves 2x2; each wave owns a 64x64 region of BOTH gate and up accumulators.
// Single-buffered, 48 KB LDS -> 3 blocks/CU (implicit cross-block overlap).
// PROVEN: 94 us, MfmaUtil 32%, VGPR 108 (rounds 0/2).
__global__ __launch_bounds__(256, 2) void k2_gateup(
    const __bf16* __restrict__ xb, const __bf16* __restrict__ gwb,
    const __bf16* __restrict__ uwb, const int* __restrict__ cnt,
    const int* __restrict__ off, const int* __restrict__ token_list,
    const int* __restrict__ jobs, const int* __restrict__ njobs,
    __bf16* __restrict__ h) {
    int jt = blockIdx.x >> 4, nt = blockIdx.x & 15;   // nt: 0..15 (DFF/128)
    if (jt >= njobs[0]) return;
    int job = jobs[jt];
    int e = job >> 6, mt = job & 63;
    int Me = cnt[e], offe = off[e];

    __shared__ __bf16 As[128 * 64];   // 16 KB
    __shared__ __bf16 Bg[128 * 64];   // 16 KB
    __shared__ __bf16 Bu[128 * 64];   // 16 KB

    int tid = threadIdx.x;
    int lane = tid & 63, w = tid >> 6;
    int wm = w >> 1, wn = w & 1;

    // staging sources: LDS slot (row, l&7) receives global k-chunk (l&7)^(row&7)
    const __bf16* asrc[4];
    const __bf16 *bsg[4], *bsu[4];
    #pragma unroll
    for (int rr = 0; rr < 4; rr++) {
        int l = rr * 256 + tid;
        int row = l >> 3, sl = l & 7;
        int gr = mt * 128 + row; if (gr >= Me) gr = Me - 1;
        int tok = token_list[e * T + gr];
        asrc[rr] = xb + (size_t)tok * H + ((sl ^ (row & 7)) * 8);
        size_t base = ((size_t)e * DFF + nt * 128 + row) * H + ((sl ^ (row & 7)) * 8);
        bsg[rr] = gwb + base;
        bsu[rr] = uwb + base;
    }

    f32x4 accg[4][4] = {};
    f32x4 accu[4][4] = {};
    int kq = lane >> 4, m15 = lane & 15;

    for (int k0 = 0; k0 < H; k0 += 64) {
        #pragma unroll
        for (int rr = 0; rr < 4; rr++) {
            gload16(asrc[rr] + k0, &As[(rr * 256 + tid) * 8]);
            gload16(bsg[rr] + k0, &Bg[(rr * 256 + tid) * 8]);
            gload16(bsu[rr] + k0, &Bu[(rr * 256 + tid) * 8]);
        }
        __syncthreads();

        #pragma unroll
        for (int kc = 0; kc < 2; kc++) {
            bf16x8 af[4], gf[4], uf[4];
            #pragma unroll
            for (int i = 0; i < 4; i++) {
                int row = wm * 64 + i * 16 + m15;
                int sl = (kc * 4 + kq) ^ (row & 7);
                af[i] = *(const bf16x8*)&As[row * 64 + sl * 8];
            }
            #pragma unroll
            for (int j = 0; j < 4; j++) {
                int row = wn * 64 + j * 16 + m15;
                int sl = (kc * 4 + kq) ^ (row & 7);
                gf[j] = *(const bf16x8*)&Bg[row * 64 + sl * 8];
                uf[j] = *(const bf16x8*)&Bu[row * 64 + sl * 8];
            }
            #pragma unroll
            for (int i = 0; i < 4; i++)
                #pragma unroll
                for (int j = 0; j < 4; j++) {
                    accg[i][j] = __builtin_amdgcn_mfma_f32_16x16x32_bf16(af[i], gf[j], accg[i][j], 0, 0, 0);
                    accu[i][j] = __builtin_amdgcn_mfma_f32_16x16x32_bf16(af[i], uf[j], accu[i][j], 0, 0, 0);
                }
        }
        __syncthreads();
    }

    // epilogue: h = silu(g) * u
    #pragma unroll
    for (int i = 0; i < 4; i++)
        #pragma unroll
        for (int j = 0; j < 4; j++) {
            int nloc = wn * 64 + j * 16 + m15;
            size_t c = (size_t)nt * 128 + nloc;
            #pragma unroll
            for (int p = 0; p < 4; p++) {
                int mloc = wm * 64 + i * 16 + kq * 4 + p;
                int mrow = mt * 128 + mloc;
                if (mrow < Me) {
                    float g = accg[i][j][p], u = accu[i][j][p];
                    float sig = 1.0f / (1.0f + __expf(-g));
                    h[(size_t)(offe + mrow) * DFF + c] = (__bf16)(g * sig * u);
                }
            }
        }
}

// ---------------- k3: grouped GEMM down (MFMA), BK=64, tile 128x128 ----------------
// 256 threads, 4 waves (2m x 2n); single-buffered 32 KB LDS, grid = jobs*8.
__global__ __launch_bounds__(256, 2) void k3_down(
    const __bf16* __restrict__ h, const __bf16* __restrict__ dwb,
    const int* __restrict__ cnt, const int* __restrict__ off,
    const int* __restrict__ jobs, const int* __restrict__ njobs,
    __bf16* __restrict__ y) {
    int jt = blockIdx.x >> 3, nt = blockIdx.x & 7;    // nt: 0..7 (H/128)
    if (jt >= njobs[0]) return;
    int job = jobs[jt];
    int e = job >> 6, mt = job & 63;
    int Me = cnt[e], offe = off[e];

    __shared__ __bf16 As[128 * 64];   // 16 KB
    __shared__ __bf16 Bs[128 * 64];   // 16 KB

    int tid = threadIdx.x;
    int lane = tid & 63, w = tid >> 6;
    int wm = w >> 1, wn = w & 1;

    const __bf16* asrc[4];
    const __bf16* bsrc[4];
    #pragma unroll
    for (int rr = 0; rr < 4; rr++) {
        int l = rr * 256 + tid;
        int row = l >> 3, sl = l & 7;
        int koff = (sl ^ (row & 7)) * 8;
        int gr = mt * 128 + row; if (gr >= Me) gr = Me - 1;
        asrc[rr] = h + (size_t)(offe + gr) * DFF + koff;
        bsrc[rr] = dwb + ((size_t)e * H + nt * 128 + row) * DFF + koff;
    }

    f32x4 acc[4][4] = {};
    int kq = lane >> 4, m15 = lane & 15;

    for (int k0 = 0; k0 < DFF; k0 += 64) {
        #pragma unroll
        for (int rr = 0; rr < 4; rr++)
            gload16(asrc[rr] + k0, &As[(rr * 256 + tid) * 8]);
        #pragma unroll
        for (int rr = 0; rr < 4; rr++)
            gload16(bsrc[rr] + k0, &Bs[(rr * 256 + tid) * 8]);
        __syncthreads();

        #pragma unroll
        for (int kc = 0; kc < 2; kc++) {
            bf16x8 af[4], bf[4];
            #pragma unroll
            for (int i = 0; i < 4; i++) {
                int row = wm * 64 + i * 16 + m15;
                int sl = (kc * 4 + kq) ^ (row & 7);
                af[i] = *(const bf16x8*)&As[row * 64 + sl * 8];
            }
            #pragma unroll
            for (int j = 0; j < 4; j++) {
                int row = wn * 64 + j * 16 + m15;
                int sl = (kc * 4 + kq) ^ (row & 7);
                bf[j] = *(const bf16x8*)&Bs[row * 64 + sl * 8];
            }
            #pragma unroll
            for (int i = 0; i < 4; i++)
                #pragma unroll
                for (int j = 0; j < 4; j++)
                    acc[i][j] = __builtin_amdgcn_mfma_f32_16x16x32_bf16(af[i], bf[j], acc[i][j], 0, 0, 0);
        }
        __syncthreads();
    }

    #pragma unroll
    for (int i = 0; i < 4; i++)
        #pragma unroll
        for (int j = 0; j < 4; j++) {
            int nglob = nt * 128 + wn * 64 + j * 16 + m15;
            #pragma unroll
            for (int p = 0; p < 4; p++) {
                int mloc = wm * 64 + i * 16 + kq * 4 + p;
                int mrow = mt * 128 + mloc;
                if (mrow < Me)
                    y[(size_t)(offe + mrow) * H + nglob] = (__bf16)acc[i][j][p];
            }
        }
}

// ---------------- gather: weighted top-2 combine -> out ----------------
__global__ __launch_bounds__(256) void k_gather(
    const __bf16* __restrict__ y, const int* __restrict__ se,
    const int* __restrict__ sp, const float* __restrict__ sw,
    const int* __restrict__ off, float* __restrict__ out) {
    int t = blockIdx.x;
    int r0 = off[se[2 * t]] + sp[2 * t];
    int r1 = off[se[2 * t + 1]] + sp[2 * t + 1];
    float w0 = sw[2 * t], w1 = sw[2 * t + 1];
    const bf16x4* y0 = (const bf16x4*)(y + (size_t)r0 * H);
    const bf16x4* y1 = (const bf16x4*)(y + (size_t)r1 * H);
    float4* o = (float4*)(out + (size_t)t * H);
    int c = threadIdx.x;
    bf16x4 a = y0[c], b = y1[c];
    float4 v;
    v.x = w0 * (float)a[0] + w1 * (float)b[0];
    v.y = w0 * (float)a[1] + w1 * (float)b[1];
    v.z = w0 * (float)a[2] + w1 * (float)b[2];
    v.w = w0 * (float)a[3] + w1 * (float)b[3];
    o[c] = v;
}

// ---------------- launch ----------------
extern "C" void kernel_launch(void* const* d_in, const int* in_sizes, int n_in,
                              void* d_out, int out_size, void* d_ws, size_t ws_size,
                              hipStream_t stream) {
    const float* x    = (const float*)d_in[0];
    const float* cent = (const float*)d_in[1];
    const float* gw   = (const float*)d_in[2];
    const float* uw   = (const float*)d_in[3];
    const float* dw   = (const float*)d_in[4];
    const float* bias = (const float*)d_in[5];
    float* out = (float*)d_out;

    // workspace layout (bytes)
    char* ws = (char*)d_ws;
    int*   cnt        = (int*)(ws + 0);
    int*   off        = (int*)(ws + 64);
    int*   se         = (int*)(ws + 128);              // 32 KB
    int*   sp         = (int*)(ws + 128 + 32768);      // 32 KB
    float* sw         = (float*)(ws + 128 + 65536);    // 32 KB
    int*   token_list = (int*)(ws + 128 + 98304);      // 128 KB
    int*   jobs       = (int*)(ws + 229504);           // 80 ints
    int*   njobs      = (int*)(ws + 229824);           // 1 int
    int*   done       = (int*)(ws + 229888);           // 1 int
    const size_t MB = 1u << 20;

    // Prefer non-aliased layout (dw converted up-front, no k_conv bubble) when
    // workspace allows; otherwise the proven aliased layout + post-k2 k_conv.
    bool bigws = (ws_size >= 154 * MB);

    __bf16 *gwb, *uwb, *dwb, *xb, *h, *y;
    if (bigws) {
        gwb = (__bf16*)(ws + 1 * MB);                  // 32 MB
        uwb = (__bf16*)(ws + 1 * MB + 33554432);       // 32 MB
        dwb = (__bf16*)(ws + 1 * MB + 67108864);       // 32 MB
        xb  = (__bf16*)(ws + 1 * MB + 100663296);      // 8 MB
        h   = (__bf16*)(ws + 1 * MB + 109051904);      // 32 MB
        y   = (__bf16*)(ws + 1 * MB + 142606336);      // 16 MB  (top = 153 MB)
    } else {
        gwb = (__bf16*)(ws + 1 * MB);                  // 32 MB
        uwb = (__bf16*)(ws + 1 * MB + 33554432);       // 32 MB
        dwb = gwb;                                     // alias: converted after k2
        y   = uwb;                                     // alias: uwb dead after k2
        xb  = (__bf16*)(ws + 1 * MB + 67108864);       // 8 MB
        h   = (__bf16*)(ws + 1 * MB + 75497472);       // 32 MB (top = 105 MB)
    }

    const int W4 = E * DFF * H / 4;
    const int X4 = T * H / 4;
    const int C3 = (bigws ? 3 : 2) * W4 + X4;

    k0_fused<<<1024 + (C3 + 255) / 256, 256, 0, stream>>>(
        x, cent, bias, se, sw, gw, gwb, uw, uwb,
        bigws ? dw : nullptr, dwb, xb, W4, X4, done);
    k1b_partition<<<E, 1024, 0, stream>>>(se, token_list, sp, cnt,
                                          off, out + (size_t)T * H, jobs, njobs, done);
    k2_gateup<<<MAXJ * 16, 256, 0, stream>>>(xb, gwb, uwb, cnt, off, token_list, jobs, njobs, h);
    if (!bigws)
        k_conv<<<(W4 + 255) / 256, 256, 0, stream>>>(dw, dwb, W4);  // aliases gwb; after k2
    k3_down<<<MAXJ * 8, 256, 0, stream>>>(h, dwb, cnt, off, jobs, njobs, y);
    k_gather<<<T, 256, 0, stream>>>(y, se, sp, sw, off, out);
}

// Round 6
// 381.826 us; speedup vs baseline: 1.5670x; 1.0504x over previous
//
#include <hip/hip_runtime.h>
#include <math.h>

// Problem constants
constexpr int E = 8, H = 1024, DFF = 2048, T = 4096;
constexpr int TR = 8192;          // total routed rows = T * topk
constexpr int MAXJ = 72;          // max (expert, m-tile) jobs: 8192/128 + E

typedef __bf16 bf16x8 __attribute__((ext_vector_type(8)));
typedef __bf16 bf16x4 __attribute__((ext_vector_type(4)));
typedef float f32x4 __attribute__((ext_vector_type(4)));

__device__ __forceinline__ void gload16(const void* g, void* l) {
    __builtin_amdgcn_global_load_lds(
        (const __attribute__((address_space(1))) unsigned int*)g,
        (__attribute__((address_space(3))) unsigned int*)l, 16, 0, 0);
}

// ---------------- k0: fused conversions (gw,uw,x -> bf16, GRID-STRIDE) + affinity ----------------
// blocks [0,1024): affinity; blocks [1024, 1024+3072): grid-stride conversion.
constexpr int CONV_BLOCKS = 3072;
__global__ __launch_bounds__(256) void k0_fused(
    const float* __restrict__ x, const float* __restrict__ cent,
    const float* __restrict__ bias,
    int* __restrict__ se, float* __restrict__ sw,
    const float* __restrict__ gw, __bf16* __restrict__ gwb,
    const float* __restrict__ uw, __bf16* __restrict__ uwb,
    __bf16* __restrict__ xb, int w4, int x4, int* __restrict__ done) {
    __shared__ float cs[E * H];
    int tid = threadIdx.x;

    if (blockIdx.x == 0 && tid == 0) *done = 0;   // reset for k1b's last-block pattern

    if (blockIdx.x >= 1024) {
        // conversion role: grid-stride over [0, 2*w4 + x4) float4s
        int total = 2 * w4 + x4;
        int stride = CONV_BLOCKS * 256;
        for (int i = (blockIdx.x - 1024) * 256 + tid; i < total; i += stride) {
            const float* in; __bf16* outp; int idx;
            if (i < w4) { in = gw; outp = gwb; idx = i; }
            else if (i < 2 * w4) { in = uw; outp = uwb; idx = i - w4; }
            else { in = x; outp = xb; idx = i - 2 * w4; }
            float4 v = ((const float4*)in)[idx];
            bf16x4 o = {(__bf16)v.x, (__bf16)v.y, (__bf16)v.z, (__bf16)v.w};
            ((bf16x4*)outp)[idx] = o;
        }
        return;
    }

    // affinity role
    for (int i = tid; i < E * H / 4; i += 256)
        ((float4*)cs)[i] = ((const float4*)cent)[i];
    __syncthreads();

    int wave = tid >> 6, lane = tid & 63;
    int t = blockIdx.x * 4 + wave;
    const float4* xr = (const float4*)(x + (size_t)t * H);
    float acc[E] = {};
    #pragma unroll
    for (int it = 0; it < 4; it++) {
        float4 xv = xr[lane + it * 64];
        #pragma unroll
        for (int e = 0; e < E; e++) {
            float4 cv = ((const float4*)(cs + e * H))[lane + it * 64];
            acc[e] = fmaf(xv.x, cv.x, acc[e]);
            acc[e] = fmaf(xv.y, cv.y, acc[e]);
            acc[e] = fmaf(xv.z, cv.z, acc[e]);
            acc[e] = fmaf(xv.w, cv.w, acc[e]);
        }
    }
    #pragma unroll
    for (int off = 32; off; off >>= 1)
        #pragma unroll
        for (int e = 0; e < E; e++) acc[e] += __shfl_down(acc[e], off);

    if (lane == 0) {
        float s[E];
        #pragma unroll
        for (int e = 0; e < E; e++)
            s[e] = 1.0f / (1.0f + expf(-acc[e])) + bias[e];
        int i0 = 0;
        for (int e = 1; e < E; e++) if (s[e] > s[i0]) i0 = e;
        int i1 = -1;
        for (int e = 0; e < E; e++) {
            if (e == i0) continue;
            if (i1 < 0 || s[e] > s[i1]) i1 = e;
        }
        float m = fmaxf(s[i0], s[i1]);
        float w0 = expf(s[i0] - m), w1 = expf(s[i1] - m);
        float inv = 1.0f / (w0 + w1);
        se[2 * t] = i0;     sw[2 * t] = w0 * inv;
        se[2 * t + 1] = i1; sw[2 * t + 1] = w1 * inv;
    }
}

// ---------------- k1b: per-expert partition + (last block) offsets/jobs ----------------
__global__ __launch_bounds__(1024) void k1b_partition(
    const int* __restrict__ se, int* __restrict__ token_list,
    int* __restrict__ sp, int* __restrict__ cnt,
    int* __restrict__ off, float* __restrict__ out_counts,
    int* __restrict__ jobs, int* __restrict__ njobs, int* __restrict__ done) {
    int e = blockIdx.x;
    int tid = threadIdx.x;
    int wave = tid >> 6, lane = tid & 63;
    __shared__ int wsum[16];
    int running = 0;
    for (int c0 = 0; c0 < 2 * T; c0 += 1024) {
        int i = c0 + tid;
        bool pred = (se[i] == e);
        unsigned long long mask = __ballot(pred);
        int pos_in_wave = __popcll(mask & ((1ull << lane) - 1ull));
        if (lane == 0) wsum[wave] = __popcll(mask);
        __syncthreads();
        int wbase = 0;
        #pragma unroll
        for (int w2 = 0; w2 < 16; w2++) {
            int v = wsum[w2];
            if (w2 < wave) wbase += v;
        }
        int total = 0;
        #pragma unroll
        for (int w2 = 0; w2 < 16; w2++) total += wsum[w2];
        if (pred) {
            int p = running + wbase + pos_in_wave;
            token_list[e * T + p] = i >> 1;
            sp[i] = p;
        }
        running += total;
        __syncthreads();
    }
    if (tid == 0) {
        __hip_atomic_store(&cnt[e], running, __ATOMIC_RELEASE, __HIP_MEMORY_SCOPE_AGENT);
        int prev = __hip_atomic_fetch_add(done, 1, __ATOMIC_ACQ_REL, __HIP_MEMORY_SCOPE_AGENT);
        if (prev == E - 1) {
            int acc = 0, nj = 0;
            for (int e2 = 0; e2 < E; e2++) {
                int c = __hip_atomic_load(&cnt[e2], __ATOMIC_ACQUIRE, __HIP_MEMORY_SCOPE_AGENT);
                off[e2] = acc; acc += c;
                out_counts[e2] = (float)c;
                int mts = (c + 127) >> 7;
                for (int mt = 0; mt < mts; mt++) jobs[nj++] = e2 * 64 + mt;
            }
            njobs[0] = nj;
        }
    }
}

// ---------------- conv: fp32 -> bf16 (dw, GRID-STRIDE; after k2, dwb aliases gwb) ----------------
constexpr int KCONV_BLOCKS = 1024;
__global__ __launch_bounds__(256) void k_conv(const float* __restrict__ in,
                                              __bf16* __restrict__ out, int n4) {
    int stride = KCONV_BLOCKS * 256;
    for (int i = blockIdx.x * 256 + threadIdx.x; i < n4; i += stride) {
        float4 v = ((const float4*)in)[i];
        bf16x4 o = {(__bf16)v.x, (__bf16)v.y, (__bf16)v.z, (__bf16)v.w};
        ((bf16x4*)out)[i] = o;
    }
}

// ---------------- k2: grouped GEMM gate+up (MFMA), BK=64, tile 128x128 dual ----------------
// PROVEN: 94 us, MfmaUtil 32%, VGPR 108 (rounds 0/2). FROZEN.
__global__ __launch_bounds__(256, 2) void k2_gateup(
    const __bf16* __restrict__ xb, const __bf16* __restrict__ gwb,
    const __bf16* __restrict__ uwb, const int* __restrict__ cnt,
    const int* __restrict__ off, const int* __restrict__ token_list,
    const int* __restrict__ jobs, const int* __restrict__ njobs,
    __bf16* __restrict__ h) {
    int jt = blockIdx.x >> 4, nt = blockIdx.x & 15;   // nt: 0..15 (DFF/128)
    if (jt >= njobs[0]) return;
    int job = jobs[jt];
    int e = job >> 6, mt = job & 63;
    int Me = cnt[e], offe = off[e];

    __shared__ __bf16 As[128 * 64];   // 16 KB
    __shared__ __bf16 Bg[128 * 64];   // 16 KB
    __shared__ __bf16 Bu[128 * 64];   // 16 KB

    int tid = threadIdx.x;
    int lane = tid & 63, w = tid >> 6;
    int wm = w >> 1, wn = w & 1;

    const __bf16* asrc[4];
    const __bf16 *bsg[4], *bsu[4];
    #pragma unroll
    for (int rr = 0; rr < 4; rr++) {
        int l = rr * 256 + tid;
        int row = l >> 3, sl = l & 7;
        int gr = mt * 128 + row; if (gr >= Me) gr = Me - 1;
        int tok = token_list[e * T + gr];
        asrc[rr] = xb + (size_t)tok * H + ((sl ^ (row & 7)) * 8);
        size_t base = ((size_t)e * DFF + nt * 128 + row) * H + ((sl ^ (row & 7)) * 8);
        bsg[rr] = gwb + base;
        bsu[rr] = uwb + base;
    }

    f32x4 accg[4][4] = {};
    f32x4 accu[4][4] = {};
    int kq = lane >> 4, m15 = lane & 15;

    for (int k0 = 0; k0 < H; k0 += 64) {
        #pragma unroll
        for (int rr = 0; rr < 4; rr++) {
            gload16(asrc[rr] + k0, &As[(rr * 256 + tid) * 8]);
            gload16(bsg[rr] + k0, &Bg[(rr * 256 + tid) * 8]);
            gload16(bsu[rr] + k0, &Bu[(rr * 256 + tid) * 8]);
        }
        __syncthreads();

        #pragma unroll
        for (int kc = 0; kc < 2; kc++) {
            bf16x8 af[4], gf[4], uf[4];
            #pragma unroll
            for (int i = 0; i < 4; i++) {
                int row = wm * 64 + i * 16 + m15;
                int sl = (kc * 4 + kq) ^ (row & 7);
                af[i] = *(const bf16x8*)&As[row * 64 + sl * 8];
            }
            #pragma unroll
            for (int j = 0; j < 4; j++) {
                int row = wn * 64 + j * 16 + m15;
                int sl = (kc * 4 + kq) ^ (row & 7);
                gf[j] = *(const bf16x8*)&Bg[row * 64 + sl * 8];
                uf[j] = *(const bf16x8*)&Bu[row * 64 + sl * 8];
            }
            #pragma unroll
            for (int i = 0; i < 4; i++)
                #pragma unroll
                for (int j = 0; j < 4; j++) {
                    accg[i][j] = __builtin_amdgcn_mfma_f32_16x16x32_bf16(af[i], gf[j], accg[i][j], 0, 0, 0);
                    accu[i][j] = __builtin_amdgcn_mfma_f32_16x16x32_bf16(af[i], uf[j], accu[i][j], 0, 0, 0);
                }
        }
        __syncthreads();
    }

    // epilogue: h = silu(g) * u
    #pragma unroll
    for (int i = 0; i < 4; i++)
        #pragma unroll
        for (int j = 0; j < 4; j++) {
            int nloc = wn * 64 + j * 16 + m15;
            size_t c = (size_t)nt * 128 + nloc;
            #pragma unroll
            for (int p = 0; p < 4; p++) {
                int mloc = wm * 64 + i * 16 + kq * 4 + p;
                int mrow = mt * 128 + mloc;
                if (mrow < Me) {
                    float g = accg[i][j][p], u = accu[i][j][p];
                    float sig = 1.0f / (1.0f + __expf(-g));
                    h[(size_t)(offe + mrow) * DFF + c] = (__bf16)(g * sig * u);
                }
            }
        }
}

// ---------------- k3: grouped GEMM down (MFMA), BK=64, tile 128x128. FROZEN. ----------------
__global__ __launch_bounds__(256, 2) void k3_down(
    const __bf16* __restrict__ h, const __bf16* __restrict__ dwb,
    const int* __restrict__ cnt, const int* __restrict__ off,
    const int* __restrict__ jobs, const int* __restrict__ njobs,
    __bf16* __restrict__ y) {
    int jt = blockIdx.x >> 3, nt = blockIdx.x & 7;    // nt: 0..7 (H/128)
    if (jt >= njobs[0]) return;
    int job = jobs[jt];
    int e = job >> 6, mt = job & 63;
    int Me = cnt[e], offe = off[e];

    __shared__ __bf16 As[128 * 64];   // 16 KB
    __shared__ __bf16 Bs[128 * 64];   // 16 KB

    int tid = threadIdx.x;
    int lane = tid & 63, w = tid >> 6;
    int wm = w >> 1, wn = w & 1;

    const __bf16* asrc[4];
    const __bf16* bsrc[4];
    #pragma unroll
    for (int rr = 0; rr < 4; rr++) {
        int l = rr * 256 + tid;
        int row = l >> 3, sl = l & 7;
        int koff = (sl ^ (row & 7)) * 8;
        int gr = mt * 128 + row; if (gr >= Me) gr = Me - 1;
        asrc[rr] = h + (size_t)(offe + gr) * DFF + koff;
        bsrc[rr] = dwb + ((size_t)e * H + nt * 128 + row) * DFF + koff;
    }

    f32x4 acc[4][4] = {};
    int kq = lane >> 4, m15 = lane & 15;

    for (int k0 = 0; k0 < DFF; k0 += 64) {
        #pragma unroll
        for (int rr = 0; rr < 4; rr++)
            gload16(asrc[rr] + k0, &As[(rr * 256 + tid) * 8]);
        #pragma unroll
        for (int rr = 0; rr < 4; rr++)
            gload16(bsrc[rr] + k0, &Bs[(rr * 256 + tid) * 8]);
        __syncthreads();

        #pragma unroll
        for (int kc = 0; kc < 2; kc++) {
            bf16x8 af[4], bf[4];
            #pragma unroll
            for (int i = 0; i < 4; i++) {
                int row = wm * 64 + i * 16 + m15;
                int sl = (kc * 4 + kq) ^ (row & 7);
                af[i] = *(const bf16x8*)&As[row * 64 + sl * 8];
            }
            #pragma unroll
            for (int j = 0; j < 4; j++) {
                int row = wn * 64 + j * 16 + m15;
                int sl = (kc * 4 + kq) ^ (row & 7);
                bf[j] = *(const bf16x8*)&Bs[row * 64 + sl * 8];
            }
            #pragma unroll
            for (int i = 0; i < 4; i++)
                #pragma unroll
                for (int j = 0; j < 4; j++)
                    acc[i][j] = __builtin_amdgcn_mfma_f32_16x16x32_bf16(af[i], bf[j], acc[i][j], 0, 0, 0);
        }
        __syncthreads();
    }

    #pragma unroll
    for (int i = 0; i < 4; i++)
        #pragma unroll
        for (int j = 0; j < 4; j++) {
            int nglob = nt * 128 + wn * 64 + j * 16 + m15;
            #pragma unroll
            for (int p = 0; p < 4; p++) {
                int mloc = wm * 64 + i * 16 + kq * 4 + p;
                int mrow = mt * 128 + mloc;
                if (mrow < Me)
                    y[(size_t)(offe + mrow) * H + nglob] = (__bf16)acc[i][j][p];
            }
        }
}

// ---------------- gather: weighted top-2 combine -> out ----------------
__global__ __launch_bounds__(256) void k_gather(
    const __bf16* __restrict__ y, const int* __restrict__ se,
    const int* __restrict__ sp, const float* __restrict__ sw,
    const int* __restrict__ off, float* __restrict__ out) {
    int t = blockIdx.x;
    int r0 = off[se[2 * t]] + sp[2 * t];
    int r1 = off[se[2 * t + 1]] + sp[2 * t + 1];
    float w0 = sw[2 * t], w1 = sw[2 * t + 1];
    const bf16x4* y0 = (const bf16x4*)(y + (size_t)r0 * H);
    const bf16x4* y1 = (const bf16x4*)(y + (size_t)r1 * H);
    float4* o = (float4*)(out + (size_t)t * H);
    int c = threadIdx.x;
    bf16x4 a = y0[c], b = y1[c];
    float4 v;
    v.x = w0 * (float)a[0] + w1 * (float)b[0];
    v.y = w0 * (float)a[1] + w1 * (float)b[1];
    v.z = w0 * (float)a[2] + w1 * (float)b[2];
    v.w = w0 * (float)a[3] + w1 * (float)b[3];
    o[c] = v;
}

// ---------------- launch ----------------
extern "C" void kernel_launch(void* const* d_in, const int* in_sizes, int n_in,
                              void* d_out, int out_size, void* d_ws, size_t ws_size,
                              hipStream_t stream) {
    const float* x    = (const float*)d_in[0];
    const float* cent = (const float*)d_in[1];
    const float* gw   = (const float*)d_in[2];
    const float* uw   = (const float*)d_in[3];
    const float* dw   = (const float*)d_in[4];
    const float* bias = (const float*)d_in[5];
    float* out = (float*)d_out;

    // workspace layout (bytes) — compact aliased layout (105 MB top)
    char* ws = (char*)d_ws;
    int*   cnt        = (int*)(ws + 0);
    int*   off        = (int*)(ws + 64);
    int*   se         = (int*)(ws + 128);              // 32 KB
    int*   sp         = (int*)(ws + 128 + 32768);      // 32 KB
    float* sw         = (float*)(ws + 128 + 65536);    // 32 KB
    int*   token_list = (int*)(ws + 128 + 98304);      // 128 KB
    int*   jobs       = (int*)(ws + 229504);           // 80 ints
    int*   njobs      = (int*)(ws + 229824);           // 1 int
    int*   done       = (int*)(ws + 229888);           // 1 int
    const size_t MB = 1u << 20;
    __bf16* gwb = (__bf16*)(ws + 1 * MB);              // 32 MB
    __bf16* uwb = (__bf16*)(ws + 1 * MB + 33554432);   // 32 MB
    __bf16* dwb = gwb;                                 // alias: converted after k2
    __bf16* y   = uwb;                                 // alias: uwb dead after k2
    __bf16* xb  = (__bf16*)(ws + 1 * MB + 67108864);   // 8 MB
    __bf16* h   = (__bf16*)(ws + 1 * MB + 75497472);   // 32 MB (top = 105 MB)

    const int W4 = E * DFF * H / 4;
    const int X4 = T * H / 4;

    k0_fused<<<1024 + CONV_BLOCKS, 256, 0, stream>>>(
        x, cent, bias, se, sw, gw, gwb, uw, uwb, xb, W4, X4, done);
    k1b_partition<<<E, 1024, 0, stream>>>(se, token_list, sp, cnt,
                                          off, out + (size_t)T * H, jobs, njobs, done);
    k2_gateup<<<MAXJ * 16, 256, 0, stream>>>(xb, gwb, uwb, cnt, off, token_list, jobs, njobs, h);
    k_conv<<<KCONV_BLOCKS, 256, 0, stream>>>(dw, dwb, W4);  // aliases gwb; after k2
    k3_down<<<MAXJ * 8, 256, 0, stream>>>(h, dwb, cnt, off, jobs, njobs, y);
    k_gather<<<T, 256, 0, stream>>>(y, se, sp, sw, off, out);
}